// Round 1
// baseline (1741.811 us; speedup 1.0000x reference)
//
#include <hip/hip_runtime.h>

typedef unsigned short u16;
typedef __attribute__((ext_vector_type(8))) __bf16 bf16x8;
typedef __attribute__((ext_vector_type(4))) float f32x4;

typedef __attribute__((address_space(1))) const void gvoid_t;
typedef __attribute__((address_space(3))) void lvoid_t;

enum { E_CADD = 1, E_BIAS = 2, E_RELU = 4, E_AFF = 8, E_WBF = 16, E_WF32 = 32 };

static __device__ __forceinline__ u16 f2bf(float f) {
  unsigned u = __float_as_uint(f);
  u += 0x7fffu + ((u >> 16) & 1u);
  return (u16)(u >> 16);
}
static __device__ __forceinline__ float bf2f(u16 h) {
  return __uint_as_float(((unsigned)h) << 16);
}

// ---------------- bf16 MFMA GEMM: C = epi(A @ Bt^T), A: 1024xK row-major bf16,
// Bt: NxK row-major bf16 (pre-transposed weights). 128x128 tile, 4 waves. ----
template <int FLAGS>
__global__ __launch_bounds__(256) void gemm_k(
    const u16* __restrict__ A, const u16* __restrict__ Bt,
    float* __restrict__ Cf, u16* __restrict__ Cb,
    const float* __restrict__ Cadd, const float* __restrict__ bias,
    const float* __restrict__ scale, const float* __restrict__ shift,
    int N, int K) {
  __shared__ u16 As[128 * 64];
  __shared__ u16 Bs[128 * 64];
  const int tid = threadIdx.x;
  const int wave = tid >> 6, lane = tid & 63;
  const int bm = blockIdx.y << 7, bn = blockIdx.x << 7;
  const int wm = (wave >> 1) << 6, wn = (wave & 1) << 6;
  const int lr = lane & 15, lg = lane >> 4;

  f32x4 acc[4][4] = {};

  for (int kt = 0; kt < K; kt += 64) {
#pragma unroll
    for (int i = 0; i < 4; ++i) {
      const int li = ((i << 2) + wave) * 64 + lane;  // 0..1023 chunk id
      const int row = li >> 3, col = (li & 7) << 3;
      const u16* gA = A + (size_t)(bm + row) * K + kt + col;
      const u16* gB = Bt + (size_t)(bn + row) * K + kt + col;
      const int lb = ((i << 2) + wave) * 512;  // wave-uniform LDS elem base
      __builtin_amdgcn_global_load_lds((gvoid_t*)gA, (lvoid_t*)(As + lb), 16, 0, 0);
      __builtin_amdgcn_global_load_lds((gvoid_t*)gB, (lvoid_t*)(Bs + lb), 16, 0, 0);
    }
    __syncthreads();
#pragma unroll
    for (int kk = 0; kk < 64; kk += 32) {
      bf16x8 av[4], bv[4];
#pragma unroll
      for (int mi = 0; mi < 4; ++mi)
        av[mi] = *(const bf16x8*)(As + ((wm + mi * 16 + lr) << 6) + kk + (lg << 3));
#pragma unroll
      for (int ni = 0; ni < 4; ++ni)
        bv[ni] = *(const bf16x8*)(Bs + ((wn + ni * 16 + lr) << 6) + kk + (lg << 3));
#pragma unroll
      for (int mi = 0; mi < 4; ++mi)
#pragma unroll
        for (int ni = 0; ni < 4; ++ni)
          acc[mi][ni] = __builtin_amdgcn_mfma_f32_16x16x32_bf16(av[mi], bv[ni], acc[mi][ni], 0, 0, 0);
    }
    __syncthreads();
  }

#pragma unroll
  for (int mi = 0; mi < 4; ++mi) {
#pragma unroll
    for (int ni = 0; ni < 4; ++ni) {
      const int col = bn + wn + ni * 16 + lr;
#pragma unroll
      for (int r = 0; r < 4; ++r) {
        const int row = bm + wm + mi * 16 + (lg << 2) + r;
        float v = acc[mi][ni][r];
        if (FLAGS & E_CADD) v += Cadd[(size_t)row * N + col];
        if (FLAGS & E_BIAS) v += bias[col];
        if (FLAGS & E_RELU) v = fmaxf(v, 0.f);
        if (FLAGS & E_AFF) v = v * scale[col] + shift[col];
        if (FLAGS & E_WF32) Cf[(size_t)row * N + col] = v;
        if (FLAGS & E_WBF) Cb[(size_t)row * N + col] = f2bf(v);
      }
    }
  }
}

// ---------------- fp32 (K,N) slice -> bf16 (N,K) transpose ----------------
__global__ __launch_bounds__(256) void transpose_cast_k(
    const float* __restrict__ in, u16* __restrict__ out,
    int ld, int k0, int K, int Nvalid) {
  __shared__ float t[64][65];
  const int kt = blockIdx.x << 6, nt = blockIdx.y << 6;
  const int tx = threadIdx.x & 63, ty = threadIdx.x >> 6;
#pragma unroll
  for (int i = 0; i < 16; ++i) {
    const int kl = ty + i * 4;
    const int n = nt + tx;
    t[kl][tx] = (n < Nvalid) ? in[(size_t)(k0 + kt + kl) * ld + n] : 0.f;
  }
  __syncthreads();
#pragma unroll
  for (int i = 0; i < 16; ++i) {
    const int n = nt + ty + i * 4;
    out[(size_t)n * K + kt + tx] = f2bf(t[tx][ty + i * 4]);
  }
}

// ---------------- pack convT(stride2,k3,SAME) weights as (N,K) bf16 GEMM mat
// out pixel p even: w[0]*x[p/2-1] + w[2]*x[p/2];  p odd: w[1]*x[(p-1)/2]
__global__ void build_packed_k(const float* __restrict__ w, const float* __restrict__ bin,
                               u16* __restrict__ wp, float* __restrict__ bp,
                               int Si, int CI, int CO) {
  const int So = Si * 2;
  const int K = Si * Si * CI;
  const int n = blockIdx.y;
  const int k = blockIdx.x * 256 + threadIdx.x;
  const int co = n % CO;
  const int pox = (n / CO) % So;
  const int poy = n / (CO * So);
  const int ci = k % CI;
  const int pix = (k / CI) % Si;
  const int piy = k / (CI * Si);
  int wy = -1, wx = -1;
  if (poy & 1) { if (piy == (poy >> 1)) wy = 1; }
  else { if (piy == (poy >> 1)) wy = 2; else if (piy == (poy >> 1) - 1) wy = 0; }
  if (pox & 1) { if (pix == (pox >> 1)) wx = 1; }
  else { if (pix == (pox >> 1)) wx = 2; else if (pix == (pox >> 1) - 1) wx = 0; }
  float v = 0.f;
  if (wy >= 0 && wx >= 0) v = w[((size_t)(wy * 3 + wx) * CI + ci) * CO + co];
  wp[(size_t)n * K + k] = f2bf(v);
  if (k == 0) bp[n] = bin[co];
}

// ---------------- featuremap pass: mean (vis0), bf16 copy ----------------
__global__ __launch_bounds__(256) void fm_pass_k(
    const float* __restrict__ fm, u16* __restrict__ fmb,
    float* __restrict__ vis_sum, u16* __restrict__ visb, int wfmb) {
  const int b = blockIdx.x;
  const int d0 = threadIdx.x << 2;
  const float* p = fm + (size_t)b * 102400 + d0;
  float s0 = 0, s1 = 0, s2 = 0, s3 = 0;
  for (int pp = 0; pp < 100; ++pp) {
    const float4 v = *(const float4*)(p + pp * 1024);
    if (wfmb) {
      ushort4 u;
      u.x = f2bf(v.x); u.y = f2bf(v.y); u.z = f2bf(v.z); u.w = f2bf(v.w);
      *(ushort4*)(fmb + (size_t)b * 102400 + pp * 1024 + d0) = u;
    }
    s0 += v.x; s1 += v.y; s2 += v.z; s3 += v.w;
  }
  const float inv = 1.0f / 100.0f;
  s0 *= inv; s1 *= inv; s2 *= inv; s3 *= inv;
  const int o = (b << 10) + d0;
  float4 m; m.x = s0; m.y = s1; m.z = s2; m.w = s3;
  *(float4*)(vis_sum + o) = m;
  ushort4 u; u.x = f2bf(s0); u.y = f2bf(s1); u.z = f2bf(s2); u.w = f2bf(s3);
  *(ushort4*)(visb + o) = u;
}

// ---------------- misc constant prep ----------------
__global__ void setup_misc_k(const float* g1, const float* be1, const float* m1, const float* v1,
                             const float* g2, const float* be2, const float* m2, const float* v2,
                             const float* bs,
                             float* scale1, float* shift1, float* scale2, float* shift2,
                             float* bs_pad) {
  const int i = blockIdx.x * 256 + threadIdx.x;
  if (i < 2048) { float sc = g1[i] * rsqrtf(v1[i] + 1e-3f); scale1[i] = sc; shift1[i] = be1[i] - m1[i] * sc; }
  if (i < 1024) { float sc = g2[i] * rsqrtf(v2[i] + 1e-3f); scale2[i] = sc; shift2[i] = be2[i] - m2[i] * sc; }
  if (i < 128) bs_pad[i] = (i < 51) ? bs[i] : 0.f;
}

__global__ void cast_k(const float* __restrict__ in, u16* __restrict__ out, int n) {
  const int i = blockIdx.x * 256 + threadIdx.x;
  if (i < n) out[i] = f2bf(in[i]);
}

// ---------------- GRU elementwise ----------------
__global__ __launch_bounds__(256) void gru_k(const float* __restrict__ mx, const float* __restrict__ mi,
                                             float* __restrict__ hf, u16* __restrict__ hb) {
  const int idx = blockIdx.x * 256 + threadIdx.x;  // B*D
  const int b = idx >> 10, d = idx & 1023;
  const float* mxb = mx + (size_t)b * 3072;
  const float* mib = mi + (size_t)b * 3072;
  const float xz = mxb[d], xr = mxb[d + 1024], xh = mxb[d + 2048];
  const float iz = mib[d], ir = mib[d + 1024], ih = mib[d + 2048];
  const float zg = 1.f / (1.f + expf(-(xz + iz)));
  const float rg = 1.f / (1.f + expf(-(xr + ir)));
  const float hh = tanhf(xh + rg * ih);
  const float hn = zg * hf[idx] + (1.f - zg) * hh;
  hf[idx] = hn;
  hb[idx] = f2bf(hn);
}

// ---------------- bilinear(16->10, antialias) + softmax(100) ----------------
static __device__ __forceinline__ void taps(int o, int& si, float* w) {
  const float s = 1.6f * (float)o + 0.3f;
  int s0 = (int)ceilf(s - 1.6f);
  if (s0 < 0) s0 = 0;
  si = s0;
  float sum = 0.f;
#pragma unroll
  for (int j = 0; j < 4; ++j) {
    const int i = s0 + j;
    float ww = 0.f;
    if (i <= 15) {
      const float d = fabsf(s - (float)i) * (1.0f / 1.6f);
      ww = fmaxf(0.f, 1.f - d);
    }
    w[j] = ww;
    sum += ww;
  }
  const float inv = 1.f / sum;
#pragma unroll
  for (int j = 0; j < 4; ++j) w[j] *= inv;
}

__global__ __launch_bounds__(128) void attn_k(const float* __restrict__ a4, float* __restrict__ attn) {
  const int b = blockIdx.x, t = threadIdx.x;
  __shared__ float sm[128];
  float val = -1e30f;
  if (t < 100) {
    const int oy = t / 10, ox = t - oy * 10;
    int siy, six;
    float wy[4], wx[4];
    taps(oy, siy, wy);
    taps(ox, six, wx);
    const float* p = a4 + (b << 8);
    float s = 0.f;
#pragma unroll
    for (int jy = 0; jy < 4; ++jy) {
      const int iy = min(siy + jy, 15);
      float rs = 0.f;
#pragma unroll
      for (int jx = 0; jx < 4; ++jx) {
        const int ix = min(six + jx, 15);
        rs += wx[jx] * p[(iy << 4) + ix];
      }
      s += wy[jy] * rs;
    }
    val = s;
  }
  sm[t] = val;
  __syncthreads();
  for (int off = 64; off > 0; off >>= 1) {
    if (t < off) sm[t] = fmaxf(sm[t], sm[t + off]);
    __syncthreads();
  }
  const float mx = sm[0];
  __syncthreads();
  const float e = (t < 100) ? expf(val - mx) : 0.f;
  sm[t] = e;
  __syncthreads();
  for (int off = 64; off > 0; off >>= 1) {
    if (t < off) sm[t] += sm[t + off];
    __syncthreads();
  }
  if (t < 100) attn[b * 100 + t] = e / sm[0];
}

// ---------------- vis = sum_p attn[p]*fm[p,:]; vis_sum += vis ----------------
__global__ __launch_bounds__(256) void wsum_bf16_k(const u16* __restrict__ fmb,
                                                   const float* __restrict__ attn,
                                                   float* __restrict__ vis_sum,
                                                   u16* __restrict__ visb) {
  const int b = blockIdx.x;
  __shared__ float at[100];
  if (threadIdx.x < 100) at[threadIdx.x] = attn[b * 100 + threadIdx.x];
  __syncthreads();
  const int d0 = threadIdx.x << 2;
  const u16* p = fmb + (size_t)b * 102400 + d0;
  float s0 = 0, s1 = 0, s2 = 0, s3 = 0;
  for (int pp = 0; pp < 100; ++pp) {
    const ushort4 v = *(const ushort4*)(p + pp * 1024);
    const float a = at[pp];
    s0 += a * bf2f(v.x); s1 += a * bf2f(v.y); s2 += a * bf2f(v.z); s3 += a * bf2f(v.w);
  }
  const int o = (b << 10) + d0;
  float4 vs = *(float4*)(vis_sum + o);
  vs.x += s0; vs.y += s1; vs.z += s2; vs.w += s3;
  *(float4*)(vis_sum + o) = vs;
  ushort4 u; u.x = f2bf(s0); u.y = f2bf(s1); u.z = f2bf(s2); u.w = f2bf(s3);
  *(ushort4*)(visb + o) = u;
}

__global__ __launch_bounds__(256) void wsum_f32_k(const float* __restrict__ fm,
                                                  const float* __restrict__ attn,
                                                  float* __restrict__ vis_sum,
                                                  u16* __restrict__ visb) {
  const int b = blockIdx.x;
  __shared__ float at[100];
  if (threadIdx.x < 100) at[threadIdx.x] = attn[b * 100 + threadIdx.x];
  __syncthreads();
  const int d0 = threadIdx.x << 2;
  const float* p = fm + (size_t)b * 102400 + d0;
  float s0 = 0, s1 = 0, s2 = 0, s3 = 0;
  for (int pp = 0; pp < 100; ++pp) {
    const float4 v = *(const float4*)(p + pp * 1024);
    const float a = at[pp];
    s0 += a * v.x; s1 += a * v.y; s2 += a * v.z; s3 += a * v.w;
  }
  const int o = (b << 10) + d0;
  float4 vs = *(float4*)(vis_sum + o);
  vs.x += s0; vs.y += s1; vs.z += s2; vs.w += s3;
  *(float4*)(vis_sum + o) = vs;
  ushort4 u; u.x = f2bf(s0); u.y = f2bf(s1); u.z = f2bf(s2); u.w = f2bf(s3);
  *(ushort4*)(visb + o) = u;
}

// ---------------- out = V/6 + score_nv + prior ----------------
__global__ void final_k(const float* __restrict__ V, const float* __restrict__ snv,
                        const float* __restrict__ prior, float* __restrict__ out) {
  const int idx = blockIdx.x * 256 + threadIdx.x;
  if (idx >= 1024 * 51) return;
  const int b = idx / 51, n = idx - b * 51;
  out[idx] = V[(b << 7) + n] * (1.f / 6.f) + snv[(b << 7) + n] + prior[idx];
}

extern "C" void kernel_launch(void* const* d_in, const int* in_sizes, int n_in,
                              void* d_out, int out_size, void* d_ws, size_t ws_size,
                              hipStream_t stream) {
  (void)in_sizes; (void)n_in; (void)out_size;
  const float* nonvis = (const float*)d_in[0];
  const float* fm     = (const float*)d_in[1];
  const float* prior  = (const float*)d_in[2];
  const float* W1     = (const float*)d_in[3];
  const float* b1     = (const float*)d_in[4];
  const float* g1     = (const float*)d_in[5];
  const float* be1    = (const float*)d_in[6];
  const float* m1     = (const float*)d_in[7];
  const float* v1     = (const float*)d_in[8];
  const float* W2     = (const float*)d_in[9];
  const float* b2     = (const float*)d_in[10];
  const float* g2     = (const float*)d_in[11];
  const float* be2    = (const float*)d_in[12];
  const float* m2     = (const float*)d_in[13];
  const float* v2     = (const float*)d_in[14];
  const float* Wk     = (const float*)d_in[15];
  const float* Uk     = (const float*)d_in[16];
  const float* bi     = (const float*)d_in[17];
  const float* br     = (const float*)d_in[18];
  const float* ct1w   = (const float*)d_in[19];
  const float* ct1b   = (const float*)d_in[20];
  const float* ct2w   = (const float*)d_in[21];
  const float* ct2b   = (const float*)d_in[22];
  const float* ct3w   = (const float*)d_in[23];
  const float* ct3b   = (const float*)d_in[24];
  const float* ct4w   = (const float*)d_in[25];
  const float* ct4b   = (const float*)d_in[26];
  const float* Ws     = (const float*)d_in[27];
  const float* bs     = (const float*)d_in[28];

  char* base = (char*)d_ws;
  size_t off = 0;
  auto alloc = [&](size_t bytes) -> void* {
    void* r = base + off;
    off = (off + bytes + 255) & ~(size_t)255;
    return r;
  };

  u16* nonvis_b = (u16*)alloc(4194304);
  u16* W1nv_t   = (u16*)alloc(8388608);
  u16* W1v_t    = (u16*)alloc(4194304);
  u16* W2t      = (u16*)alloc(4194304);
  u16* Wkt      = (u16*)alloc(6291456);
  u16* Ukt      = (u16*)alloc(6291456);
  u16* Wsnv_t   = (u16*)alloc(524288);
  u16* Wsv_t    = (u16*)alloc(262144);
  u16* Wp1      = (u16*)alloc(2097152);
  u16* Wp2      = (u16*)alloc(2097152);
  u16* Wp3      = (u16*)alloc(2097152);
  u16* Wp4      = (u16*)alloc(524288);
  float* bp1    = (float*)alloc(4096);
  float* bp2    = (float*)alloc(4096);
  float* bp3    = (float*)alloc(4096);
  float* bp4    = (float*)alloc(1024);
  float* scale1 = (float*)alloc(8192);
  float* shift1 = (float*)alloc(8192);
  float* scale2 = (float*)alloc(4096);
  float* shift2 = (float*)alloc(4096);
  float* bs_pad = (float*)alloc(512);
  float* P1     = (float*)alloc(8388608);
  float* snv    = (float*)alloc(524288);
  u16* x1       = (u16*)alloc(4194304);
  u16* x2       = (u16*)alloc(2097152);
  float* mx     = (float*)alloc(12582912);
  float* mi     = (float*)alloc(12582912);
  float* hf     = (float*)alloc(4194304);
  u16* hb       = (u16*)alloc(2097152);
  u16* a1       = (u16*)alloc(2097152);
  u16* a2       = (u16*)alloc(2097152);
  u16* a3       = (u16*)alloc(2097152);
  float* a4     = (float*)alloc(1048576);
  float* attn   = (float*)alloc(409600);
  float* vis_sum= (float*)alloc(4194304);
  u16* visb     = (u16*)alloc(2097152);
  u16* vsb      = (u16*)alloc(2097152);
  float* V      = (float*)alloc(524288);
  u16* fmb = nullptr;
  int use_fmb = 0;
  if (off + (size_t)209715200 + 256 <= ws_size) {
    fmb = (u16*)alloc(209715200);
    use_fmb = 1;
  }

  // ---- setup ----
  hipMemsetAsync(hf, 0, 4194304, stream);
  hipMemsetAsync(hb, 0, 2097152, stream);
  fm_pass_k<<<1024, 256, 0, stream>>>(fm, fmb, vis_sum, visb, use_fmb);
  cast_k<<<8192, 256, 0, stream>>>(nonvis, nonvis_b, 2097152);
  setup_misc_k<<<8, 256, 0, stream>>>(g1, be1, m1, v1, g2, be2, m2, v2, bs,
                                      scale1, shift1, scale2, shift2, bs_pad);
  transpose_cast_k<<<dim3(32, 32), 256, 0, stream>>>(W1, W1nv_t, 2048, 0, 2048, 2048);
  transpose_cast_k<<<dim3(16, 32), 256, 0, stream>>>(W1, W1v_t, 2048, 2048, 1024, 2048);
  transpose_cast_k<<<dim3(32, 16), 256, 0, stream>>>(W2, W2t, 1024, 0, 2048, 1024);
  transpose_cast_k<<<dim3(16, 48), 256, 0, stream>>>(Wk, Wkt, 3072, 0, 1024, 3072);
  transpose_cast_k<<<dim3(16, 48), 256, 0, stream>>>(Uk, Ukt, 3072, 0, 1024, 3072);
  transpose_cast_k<<<dim3(32, 2), 256, 0, stream>>>(Ws, Wsnv_t, 51, 0, 2048, 51);
  transpose_cast_k<<<dim3(16, 2), 256, 0, stream>>>(Ws, Wsv_t, 51, 2048, 1024, 51);
  build_packed_k<<<dim3(4, 1024), 256, 0, stream>>>(ct1w, ct1b, Wp1, bp1, 1, 1024, 256);
  build_packed_k<<<dim3(4, 1024), 256, 0, stream>>>(ct2w, ct2b, Wp2, bp2, 2, 256, 64);
  build_packed_k<<<dim3(4, 1024), 256, 0, stream>>>(ct3w, ct3b, Wp3, bp3, 4, 64, 16);
  build_packed_k<<<dim3(4, 256), 256, 0, stream>>>(ct4w, ct4b, Wp4, bp4, 8, 16, 1);

  // P1 = nonvis @ W1[:2048,:] + b1 ; snv = nonvis @ Ws[:2048,:] + bs
  gemm_k<E_BIAS | E_WF32><<<dim3(16, 8), 256, 0, stream>>>(
      nonvis_b, W1nv_t, P1, nullptr, nullptr, b1, nullptr, nullptr, 2048, 2048);
  gemm_k<E_BIAS | E_WF32><<<dim3(1, 8), 256, 0, stream>>>(
      nonvis_b, Wsnv_t, snv, nullptr, nullptr, bs_pad, nullptr, nullptr, 128, 2048);

  // ---- 5 iterations ----
  for (int it = 0; it < 5; ++it) {
    gemm_k<E_CADD | E_RELU | E_AFF | E_WBF><<<dim3(16, 8), 256, 0, stream>>>(
        visb, W1v_t, nullptr, x1, P1, nullptr, scale1, shift1, 2048, 1024);
    gemm_k<E_BIAS | E_RELU | E_AFF | E_WBF><<<dim3(8, 8), 256, 0, stream>>>(
        x1, W2t, nullptr, x2, nullptr, b2, scale2, shift2, 1024, 2048);
    gemm_k<E_BIAS | E_WF32><<<dim3(24, 8), 256, 0, stream>>>(
        x2, Wkt, mx, nullptr, nullptr, bi, nullptr, nullptr, 3072, 1024);
    gemm_k<E_BIAS | E_WF32><<<dim3(24, 8), 256, 0, stream>>>(
        hb, Ukt, mi, nullptr, nullptr, br, nullptr, nullptr, 3072, 1024);
    gru_k<<<4096, 256, 0, stream>>>(mx, mi, hf, hb);
    gemm_k<E_BIAS | E_RELU | E_WBF><<<dim3(8, 8), 256, 0, stream>>>(
        hb, Wp1, nullptr, a1, nullptr, bp1, nullptr, nullptr, 1024, 1024);
    gemm_k<E_BIAS | E_RELU | E_WBF><<<dim3(8, 8), 256, 0, stream>>>(
        a1, Wp2, nullptr, a2, nullptr, bp2, nullptr, nullptr, 1024, 1024);
    gemm_k<E_BIAS | E_RELU | E_WBF><<<dim3(8, 8), 256, 0, stream>>>(
        a2, Wp3, nullptr, a3, nullptr, bp3, nullptr, nullptr, 1024, 1024);
    gemm_k<E_BIAS | E_WF32><<<dim3(2, 8), 256, 0, stream>>>(
        a3, Wp4, a4, nullptr, nullptr, bp4, nullptr, nullptr, 256, 1024);
    attn_k<<<1024, 128, 0, stream>>>(a4, attn);
    if (use_fmb)
      wsum_bf16_k<<<1024, 256, 0, stream>>>(fmb, attn, vis_sum, visb);
    else
      wsum_f32_k<<<1024, 256, 0, stream>>>(fm, attn, vis_sum, visb);
  }

  // ---- final: out = snv + (vis_sum @ Wsv)/6 + prior ----
  cast_k<<<4096, 256, 0, stream>>>(vis_sum, vsb, 1048576);
  gemm_k<E_WF32><<<dim3(1, 8), 256, 0, stream>>>(
      vsb, Wsv_t, V, nullptr, nullptr, nullptr, nullptr, nullptr, 128, 1024);
  final_k<<<204, 256, 0, stream>>>(V, snv, prior, (float*)d_out);
}

// Round 2
// 1150.332 us; speedup vs baseline: 1.5142x; 1.5142x over previous
//
#include <hip/hip_runtime.h>

typedef unsigned short u16;
typedef __attribute__((ext_vector_type(8))) __bf16 bf16x8;
typedef __attribute__((ext_vector_type(4))) float f32x4;

typedef __attribute__((address_space(1))) const void gvoid_t;
typedef __attribute__((address_space(3))) void lvoid_t;

enum { E_CADD = 1, E_BIAS = 2, E_RELU = 4, E_AFF = 8, E_WBF = 16, E_WF32 = 32 };

static __device__ __forceinline__ u16 f2bf(float f) {
  unsigned u = __float_as_uint(f);
  u += 0x7fffu + ((u >> 16) & 1u);
  return (u16)(u >> 16);
}
static __device__ __forceinline__ float bf2f(u16 h) {
  return __uint_as_float(((unsigned)h) << 16);
}

// ---------------- 64x64-tile bf16 MFMA GEMM body -----------------------------
// C = epi(A @ Bt^T). A: M x K row-major bf16, Bt: N x K row-major bf16.
// 4 waves, each 32x32 (2x2 frags). LDS tiles XOR-swizzled: linear gload_lds
// dest + pre-swizzled SOURCE column-group, same XOR on ds_read (rule 21 / T2).
template <int FLAGS>
static __device__ __forceinline__ void gemm64_body(
    u16* As, u16* Bs,
    const u16* __restrict__ A, const u16* __restrict__ Bt,
    float* __restrict__ Cf, u16* __restrict__ Cb,
    const float* __restrict__ Cadd, const float* __restrict__ bias,
    const float* __restrict__ scale, const float* __restrict__ shift,
    int N, int K, int bx, int by) {
  const int tid = threadIdx.x;
  const int wave = tid >> 6, lane = tid & 63;
  const int bm = by << 6, bn = bx << 6;
  const int wm = (wave >> 1) << 5, wn = (wave & 1) << 5;
  const int lr = lane & 15, lg = lane >> 4;
  const int rx = lr & 7;  // row&7 for the swizzled read

  f32x4 acc[2][2] = {};

  for (int kt = 0; kt < K; kt += 64) {
#pragma unroll
    for (int i = 0; i < 2; ++i) {
      const int li = i * 256 + tid;
      const int row = li >> 3;
      const int cg = (li & 7) ^ (row & 7);            // swizzled source col-grp
      const int lb = (i * 256 + wave * 64) * 8;       // wave-uniform LDS base
      __builtin_amdgcn_global_load_lds(
          (gvoid_t*)(A + (size_t)(bm + row) * K + kt + (cg << 3)),
          (lvoid_t*)(As + lb), 16, 0, 0);
      __builtin_amdgcn_global_load_lds(
          (gvoid_t*)(Bt + (size_t)(bn + row) * K + kt + (cg << 3)),
          (lvoid_t*)(Bs + lb), 16, 0, 0);
    }
    __syncthreads();
#pragma unroll
    for (int kk = 0; kk < 64; kk += 32) {
      bf16x8 av[2], bv[2];
#pragma unroll
      for (int mi = 0; mi < 2; ++mi)
        av[mi] = *(const bf16x8*)(As + ((wm + mi * 16 + lr) << 6) +
                                  ((((kk >> 3) + lg) ^ rx) << 3));
#pragma unroll
      for (int ni = 0; ni < 2; ++ni)
        bv[ni] = *(const bf16x8*)(Bs + ((wn + ni * 16 + lr) << 6) +
                                  ((((kk >> 3) + lg) ^ rx) << 3));
#pragma unroll
      for (int mi = 0; mi < 2; ++mi)
#pragma unroll
        for (int ni = 0; ni < 2; ++ni)
          acc[mi][ni] = __builtin_amdgcn_mfma_f32_16x16x32_bf16(av[mi], bv[ni], acc[mi][ni], 0, 0, 0);
    }
    __syncthreads();
  }

#pragma unroll
  for (int mi = 0; mi < 2; ++mi) {
#pragma unroll
    for (int ni = 0; ni < 2; ++ni) {
      const int col = bn + wn + ni * 16 + lr;
#pragma unroll
      for (int r = 0; r < 4; ++r) {
        const int row = bm + wm + mi * 16 + (lg << 2) + r;
        float v = acc[mi][ni][r];
        if (FLAGS & E_CADD) v += Cadd[(size_t)row * N + col];
        if (FLAGS & E_BIAS) v += bias[col];
        if (FLAGS & E_RELU) v = fmaxf(v, 0.f);
        if (FLAGS & E_AFF) v = v * scale[col] + shift[col];
        if (FLAGS & E_WF32) Cf[(size_t)row * N + col] = v;
        if (FLAGS & E_WBF) Cb[(size_t)row * N + col] = f2bf(v);
      }
    }
  }
}

template <int FLAGS>
__global__ __launch_bounds__(256) void gemm64_k(
    const u16* __restrict__ A, const u16* __restrict__ Bt,
    float* __restrict__ Cf, u16* __restrict__ Cb,
    const float* __restrict__ Cadd, const float* __restrict__ bias,
    const float* __restrict__ scale, const float* __restrict__ shift,
    int N, int K) {
  __shared__ u16 As[4096], Bs[4096];
  gemm64_body<FLAGS>(As, Bs, A, Bt, Cf, Cb, Cadd, bias, scale, shift, N, K,
                     blockIdx.x, blockIdx.y);
}

// Two independent GEMMs in one launch (blockIdx.z selects).
template <int F0, int F1>
__global__ __launch_bounds__(256) void gemm64_pair_k(
    const u16* A0, const u16* B0, float* Cf0, u16* Cb0, const float* Cadd0,
    const float* bias0, const float* scale0, const float* shift0, int N0, int K0, int xt0,
    const u16* A1, const u16* B1, float* Cf1, u16* Cb1, const float* Cadd1,
    const float* bias1, const float* scale1, const float* shift1, int N1, int K1, int xt1) {
  __shared__ u16 As[4096], Bs[4096];
  if (blockIdx.z == 0) {
    if ((int)blockIdx.x < xt0)
      gemm64_body<F0>(As, Bs, A0, B0, Cf0, Cb0, Cadd0, bias0, scale0, shift0,
                      N0, K0, blockIdx.x, blockIdx.y);
  } else {
    if ((int)blockIdx.x < xt1)
      gemm64_body<F1>(As, Bs, A1, B1, Cf1, Cb1, Cadd1, bias1, scale1, shift1,
                      N1, K1, blockIdx.x, blockIdx.y);
  }
}

// ---------------- all weight transposes (fp32 (K,N) slice -> bf16 (N,K)) ----
__global__ __launch_bounds__(256) void prep_w_k(
    const float* __restrict__ W1, const float* __restrict__ W2,
    const float* __restrict__ Wk, const float* __restrict__ Uk,
    const float* __restrict__ Ws,
    u16* __restrict__ W1nv_t, u16* __restrict__ W1v_t, u16* __restrict__ W2t,
    u16* __restrict__ Wkt, u16* __restrict__ Ukt,
    u16* __restrict__ Wsnv_t, u16* __restrict__ Wsv_t) {
  int b = blockIdx.x;
  const float* in; u16* out; int ld, k0, K, Nv, kT;
  if (b < 1024)      {           in = W1; out = W1nv_t; ld = 2048; k0 = 0;    K = 2048; Nv = 2048; kT = 32; }
  else if (b < 1536) { b -= 1024; in = W1; out = W1v_t;  ld = 2048; k0 = 2048; K = 1024; Nv = 2048; kT = 16; }
  else if (b < 2048) { b -= 1536; in = W2; out = W2t;   ld = 1024; k0 = 0;    K = 2048; Nv = 1024; kT = 32; }
  else if (b < 2816) { b -= 2048; in = Wk; out = Wkt;   ld = 3072; k0 = 0;    K = 1024; Nv = 3072; kT = 16; }
  else if (b < 3584) { b -= 2816; in = Uk; out = Ukt;   ld = 3072; k0 = 0;    K = 1024; Nv = 3072; kT = 16; }
  else if (b < 3648) { b -= 3584; in = Ws; out = Wsnv_t; ld = 51;  k0 = 0;    K = 2048; Nv = 51;   kT = 32; }
  else               { b -= 3648; in = Ws; out = Wsv_t;  ld = 51;  k0 = 2048; K = 1024; Nv = 51;   kT = 16; }
  const int kt = (b % kT) << 6, nt = (b / kT) << 6;
  __shared__ float t[64][65];
  const int tx = threadIdx.x & 63, ty = threadIdx.x >> 6;
#pragma unroll
  for (int i = 0; i < 16; ++i) {
    const int kl = ty + i * 4;
    const int n = nt + tx;
    t[kl][tx] = (n < Nv) ? in[(size_t)(k0 + kt + kl) * ld + n] : 0.f;
  }
  __syncthreads();
#pragma unroll
  for (int i = 0; i < 16; ++i)
    out[(size_t)(nt + ty + i * 4) * K + kt + tx] = f2bf(t[tx][ty + i * 4]);
}

// ---------------- pack all 4 convT(stride2,k3,SAME) weight layers ------------
// out pixel p even: w[0]*x[p/2-1] + w[2]*x[p/2];  p odd: w[1]*x[(p-1)/2]
__global__ void build_all_k(
    const float* __restrict__ w1, const float* __restrict__ b1c,
    const float* __restrict__ w2, const float* __restrict__ b2c,
    const float* __restrict__ w3, const float* __restrict__ b3c,
    const float* __restrict__ w4, const float* __restrict__ b4c,
    u16* __restrict__ Wp1, u16* __restrict__ Wp2,
    u16* __restrict__ Wp3, u16* __restrict__ Wp4,
    float* __restrict__ bp1, float* __restrict__ bp2,
    float* __restrict__ bp3, float* __restrict__ bp4) {
  int y = blockIdx.y;
  const float* w; const float* bin; u16* wp; float* bp; int Si, CI, CO, n;
  if (y < 1024)      { n = y;        w = w1; bin = b1c; wp = Wp1; bp = bp1; Si = 1; CI = 1024; CO = 256; }
  else if (y < 2048) { n = y - 1024; w = w2; bin = b2c; wp = Wp2; bp = bp2; Si = 2; CI = 256;  CO = 64; }
  else if (y < 3072) { n = y - 2048; w = w3; bin = b3c; wp = Wp3; bp = bp3; Si = 4; CI = 64;   CO = 16; }
  else               { n = y - 3072; w = w4; bin = b4c; wp = Wp4; bp = bp4; Si = 8; CI = 16;   CO = 1; }
  const int So = Si * 2;
  const int K = Si * Si * CI;  // = 1024 for all layers
  const int k = blockIdx.x * 256 + threadIdx.x;
  const int co = n % CO;
  const int pox = (n / CO) % So;
  const int poy = n / (CO * So);
  const int ci = k % CI;
  const int pix = (k / CI) % Si;
  const int piy = k / (CI * Si);
  int wy = -1, wx = -1;
  if (poy & 1) { if (piy == (poy >> 1)) wy = 1; }
  else { if (piy == (poy >> 1)) wy = 2; else if (piy == (poy >> 1) - 1) wy = 0; }
  if (pox & 1) { if (pix == (pox >> 1)) wx = 1; }
  else { if (pix == (pox >> 1)) wx = 2; else if (pix == (pox >> 1) - 1) wx = 0; }
  float v = 0.f;
  if (wy >= 0 && wx >= 0) v = w[((size_t)(wy * 3 + wx) * CI + ci) * CO + co];
  wp[(size_t)n * K + k] = f2bf(v);
  if (k == 0) bp[n] = bin[co];
}

// ---------------- featuremap pass: mean (vis0), bf16 copy ----------------
__global__ __launch_bounds__(256) void fm_pass_k(
    const float* __restrict__ fm, u16* __restrict__ fmb,
    float* __restrict__ vis_sum, u16* __restrict__ visb, int wfmb) {
  const int b = blockIdx.x;
  const int d0 = threadIdx.x << 2;
  const float* p = fm + (size_t)b * 102400 + d0;
  float s0 = 0, s1 = 0, s2 = 0, s3 = 0;
  for (int pp = 0; pp < 100; ++pp) {
    const float4 v = *(const float4*)(p + pp * 1024);
    if (wfmb) {
      ushort4 u;
      u.x = f2bf(v.x); u.y = f2bf(v.y); u.z = f2bf(v.z); u.w = f2bf(v.w);
      *(ushort4*)(fmb + (size_t)b * 102400 + pp * 1024 + d0) = u;
    }
    s0 += v.x; s1 += v.y; s2 += v.z; s3 += v.w;
  }
  const float inv = 1.0f / 100.0f;
  s0 *= inv; s1 *= inv; s2 *= inv; s3 *= inv;
  const int o = (b << 10) + d0;
  float4 m; m.x = s0; m.y = s1; m.z = s2; m.w = s3;
  *(float4*)(vis_sum + o) = m;
  ushort4 u; u.x = f2bf(s0); u.y = f2bf(s1); u.z = f2bf(s2); u.w = f2bf(s3);
  *(ushort4*)(visb + o) = u;
}

// ---------------- nonvis cast + BN constants + h init ----------------
__global__ __launch_bounds__(256) void misc_k(
    const float* __restrict__ nonvis, u16* __restrict__ nonvis_b,
    const float* g1, const float* be1, const float* m1, const float* v1,
    const float* g2, const float* be2, const float* m2, const float* v2,
    const float* bs, float* scale1, float* shift1, float* scale2, float* shift2,
    float* bs_pad, float* __restrict__ hf, u16* __restrict__ hb) {
  const int i = blockIdx.x * 256 + threadIdx.x;
  if (i < 2097152) nonvis_b[i] = f2bf(nonvis[i]);
  if (i < 1048576) { hf[i] = 0.f; hb[i] = 0; }
  if (i < 2048) { float sc = g1[i] * rsqrtf(v1[i] + 1e-3f); scale1[i] = sc; shift1[i] = be1[i] - m1[i] * sc; }
  if (i < 1024) { float sc = g2[i] * rsqrtf(v2[i] + 1e-3f); scale2[i] = sc; shift2[i] = be2[i] - m2[i] * sc; }
  if (i < 128) bs_pad[i] = (i < 51) ? bs[i] : 0.f;
}

// ---------------- GRU elementwise ----------------
__global__ __launch_bounds__(256) void gru_k(const float* __restrict__ mx, const float* __restrict__ mi,
                                             float* __restrict__ hf, u16* __restrict__ hb) {
  const int idx = blockIdx.x * 256 + threadIdx.x;  // B*D
  const int b = idx >> 10, d = idx & 1023;
  const float* mxb = mx + (size_t)b * 3072;
  const float* mib = mi + (size_t)b * 3072;
  const float xz = mxb[d], xr = mxb[d + 1024], xh = mxb[d + 2048];
  const float iz = mib[d], ir = mib[d + 1024], ih = mib[d + 2048];
  const float zg = 1.f / (1.f + expf(-(xz + iz)));
  const float rg = 1.f / (1.f + expf(-(xr + ir)));
  const float hh = tanhf(xh + rg * ih);
  const float hn = zg * hf[idx] + (1.f - zg) * hh;
  hf[idx] = hn;
  hb[idx] = f2bf(hn);
}

// ---------------- bilinear(16->10, antialias) + softmax(100) ----------------
static __device__ __forceinline__ void taps(int o, int& si, float* w) {
  const float s = 1.6f * (float)o + 0.3f;
  int s0 = (int)ceilf(s - 1.6f);
  if (s0 < 0) s0 = 0;
  si = s0;
  float sum = 0.f;
#pragma unroll
  for (int j = 0; j < 4; ++j) {
    const int i = s0 + j;
    float ww = 0.f;
    if (i <= 15) {
      const float d = fabsf(s - (float)i) * (1.0f / 1.6f);
      ww = fmaxf(0.f, 1.f - d);
    }
    w[j] = ww;
    sum += ww;
  }
  const float inv = 1.f / sum;
#pragma unroll
  for (int j = 0; j < 4; ++j) w[j] *= inv;
}

__global__ __launch_bounds__(128) void attn_k(const float* __restrict__ a4, float* __restrict__ attn) {
  const int b = blockIdx.x, t = threadIdx.x;
  __shared__ float sm[128];
  float val = -1e30f;
  if (t < 100) {
    const int oy = t / 10, ox = t - oy * 10;
    int siy, six;
    float wy[4], wx[4];
    taps(oy, siy, wy);
    taps(ox, six, wx);
    const float* p = a4 + (b << 8);
    float s = 0.f;
#pragma unroll
    for (int jy = 0; jy < 4; ++jy) {
      const int iy = min(siy + jy, 15);
      float rs = 0.f;
#pragma unroll
      for (int jx = 0; jx < 4; ++jx) {
        const int ix = min(six + jx, 15);
        rs += wx[jx] * p[(iy << 4) + ix];
      }
      s += wy[jy] * rs;
    }
    val = s;
  }
  sm[t] = val;
  __syncthreads();
  for (int off = 64; off > 0; off >>= 1) {
    if (t < off) sm[t] = fmaxf(sm[t], sm[t + off]);
    __syncthreads();
  }
  const float mx = sm[0];
  __syncthreads();
  const float e = (t < 100) ? expf(val - mx) : 0.f;
  sm[t] = e;
  __syncthreads();
  for (int off = 64; off > 0; off >>= 1) {
    if (t < off) sm[t] += sm[t + off];
    __syncthreads();
  }
  if (t < 100) attn[b * 100 + t] = e / sm[0];
}

// ------- vis = sum_p attn[p]*fm[p,:]; vis_sum += vis; vsb = bf16(vis_sum) ----
__global__ __launch_bounds__(256) void wsum_bf16_k(const u16* __restrict__ fmb,
                                                   const float* __restrict__ attn,
                                                   float* __restrict__ vis_sum,
                                                   u16* __restrict__ visb,
                                                   u16* __restrict__ vsb) {
  const int b = blockIdx.x;
  __shared__ float at[100];
  if (threadIdx.x < 100) at[threadIdx.x] = attn[b * 100 + threadIdx.x];
  __syncthreads();
  const int d0 = threadIdx.x << 2;
  const u16* p = fmb + (size_t)b * 102400 + d0;
  float s0 = 0, s1 = 0, s2 = 0, s3 = 0;
  for (int pp = 0; pp < 100; ++pp) {
    const ushort4 v = *(const ushort4*)(p + pp * 1024);
    const float a = at[pp];
    s0 += a * bf2f(v.x); s1 += a * bf2f(v.y); s2 += a * bf2f(v.z); s3 += a * bf2f(v.w);
  }
  const int o = (b << 10) + d0;
  float4 vs = *(float4*)(vis_sum + o);
  vs.x += s0; vs.y += s1; vs.z += s2; vs.w += s3;
  *(float4*)(vis_sum + o) = vs;
  ushort4 u; u.x = f2bf(s0); u.y = f2bf(s1); u.z = f2bf(s2); u.w = f2bf(s3);
  *(ushort4*)(visb + o) = u;
  ushort4 w; w.x = f2bf(vs.x); w.y = f2bf(vs.y); w.z = f2bf(vs.z); w.w = f2bf(vs.w);
  *(ushort4*)(vsb + o) = w;
}

__global__ __launch_bounds__(256) void wsum_f32_k(const float* __restrict__ fm,
                                                  const float* __restrict__ attn,
                                                  float* __restrict__ vis_sum,
                                                  u16* __restrict__ visb,
                                                  u16* __restrict__ vsb) {
  const int b = blockIdx.x;
  __shared__ float at[100];
  if (threadIdx.x < 100) at[threadIdx.x] = attn[b * 100 + threadIdx.x];
  __syncthreads();
  const int d0 = threadIdx.x << 2;
  const float* p = fm + (size_t)b * 102400 + d0;
  float s0 = 0, s1 = 0, s2 = 0, s3 = 0;
  for (int pp = 0; pp < 100; ++pp) {
    const float4 v = *(const float4*)(p + pp * 1024);
    const float a = at[pp];
    s0 += a * v.x; s1 += a * v.y; s2 += a * v.z; s3 += a * v.w;
  }
  const int o = (b << 10) + d0;
  float4 vs = *(float4*)(vis_sum + o);
  vs.x += s0; vs.y += s1; vs.z += s2; vs.w += s3;
  *(float4*)(vis_sum + o) = vs;
  ushort4 u; u.x = f2bf(s0); u.y = f2bf(s1); u.z = f2bf(s2); u.w = f2bf(s3);
  *(ushort4*)(visb + o) = u;
  ushort4 w; w.x = f2bf(vs.x); w.y = f2bf(vs.y); w.z = f2bf(vs.z); w.w = f2bf(vs.w);
  *(ushort4*)(vsb + o) = w;
}

// ---------------- out = V/6 + score_nv + prior ----------------
__global__ void final_k(const float* __restrict__ V, const float* __restrict__ snv,
                        const float* __restrict__ prior, float* __restrict__ out) {
  const int idx = blockIdx.x * 256 + threadIdx.x;
  if (idx >= 1024 * 51) return;
  const int b = idx / 51, n = idx - b * 51;
  out[idx] = V[(b << 7) + n] * (1.f / 6.f) + snv[(b << 7) + n] + prior[idx];
}

extern "C" void kernel_launch(void* const* d_in, const int* in_sizes, int n_in,
                              void* d_out, int out_size, void* d_ws, size_t ws_size,
                              hipStream_t stream) {
  (void)in_sizes; (void)n_in; (void)out_size;
  const float* nonvis = (const float*)d_in[0];
  const float* fm     = (const float*)d_in[1];
  const float* prior  = (const float*)d_in[2];
  const float* W1     = (const float*)d_in[3];
  const float* b1     = (const float*)d_in[4];
  const float* g1     = (const float*)d_in[5];
  const float* be1    = (const float*)d_in[6];
  const float* m1     = (const float*)d_in[7];
  const float* v1     = (const float*)d_in[8];
  const float* W2     = (const float*)d_in[9];
  const float* b2     = (const float*)d_in[10];
  const float* g2     = (const float*)d_in[11];
  const float* be2    = (const float*)d_in[12];
  const float* m2     = (const float*)d_in[13];
  const float* v2     = (const float*)d_in[14];
  const float* Wk     = (const float*)d_in[15];
  const float* Uk     = (const float*)d_in[16];
  const float* bi     = (const float*)d_in[17];
  const float* br     = (const float*)d_in[18];
  const float* ct1w   = (const float*)d_in[19];
  const float* ct1b   = (const float*)d_in[20];
  const float* ct2w   = (const float*)d_in[21];
  const float* ct2b   = (const float*)d_in[22];
  const float* ct3w   = (const float*)d_in[23];
  const float* ct3b   = (const float*)d_in[24];
  const float* ct4w   = (const float*)d_in[25];
  const float* ct4b   = (const float*)d_in[26];
  const float* Ws     = (const float*)d_in[27];
  const float* bs     = (const float*)d_in[28];

  char* base = (char*)d_ws;
  size_t off = 0;
  auto alloc = [&](size_t bytes) -> void* {
    void* r = base + off;
    off = (off + bytes + 255) & ~(size_t)255;
    return r;
  };

  u16* nonvis_b = (u16*)alloc(4194304);
  u16* W1nv_t   = (u16*)alloc(8388608);
  u16* W1v_t    = (u16*)alloc(4194304);
  u16* W2t      = (u16*)alloc(4194304);
  u16* Wkt      = (u16*)alloc(6291456);
  u16* Ukt      = (u16*)alloc(6291456);
  u16* Wsnv_t   = (u16*)alloc(524288);
  u16* Wsv_t    = (u16*)alloc(262144);
  u16* Wp1      = (u16*)alloc(2097152);
  u16* Wp2      = (u16*)alloc(2097152);
  u16* Wp3      = (u16*)alloc(2097152);
  u16* Wp4      = (u16*)alloc(524288);
  float* bp1    = (float*)alloc(4096);
  float* bp2    = (float*)alloc(4096);
  float* bp3    = (float*)alloc(4096);
  float* bp4    = (float*)alloc(1024);
  float* scale1 = (float*)alloc(8192);
  float* shift1 = (float*)alloc(8192);
  float* scale2 = (float*)alloc(4096);
  float* shift2 = (float*)alloc(4096);
  float* bs_pad = (float*)alloc(512);
  float* P1     = (float*)alloc(8388608);
  float* snv    = (float*)alloc(524288);
  u16* x1       = (u16*)alloc(4194304);
  u16* x2       = (u16*)alloc(2097152);
  float* mx     = (float*)alloc(12582912);
  float* mi     = (float*)alloc(12582912);
  float* hf     = (float*)alloc(4194304);
  u16* hb       = (u16*)alloc(2097152);
  u16* a1       = (u16*)alloc(2097152);
  u16* a2       = (u16*)alloc(2097152);
  u16* a3       = (u16*)alloc(2097152);
  float* a4     = (float*)alloc(1048576);
  float* attn   = (float*)alloc(409600);
  float* vis_sum= (float*)alloc(4194304);
  u16* visb     = (u16*)alloc(2097152);
  u16* vsb      = (u16*)alloc(2097152);
  float* V      = (float*)alloc(524288);
  u16* fmb = nullptr;
  int use_fmb = 0;
  if (off + (size_t)209715200 + 256 <= ws_size) {
    fmb = (u16*)alloc(209715200);
    use_fmb = 1;
  }

  // ---- setup ----
  misc_k<<<8192, 256, 0, stream>>>(nonvis, nonvis_b, g1, be1, m1, v1, g2, be2, m2, v2,
                                   bs, scale1, shift1, scale2, shift2, bs_pad, hf, hb);
  prep_w_k<<<3680, 256, 0, stream>>>(W1, W2, Wk, Uk, Ws,
                                     W1nv_t, W1v_t, W2t, Wkt, Ukt, Wsnv_t, Wsv_t);
  build_all_k<<<dim3(4, 3328), 256, 0, stream>>>(ct1w, ct1b, ct2w, ct2b, ct3w, ct3b, ct4w, ct4b,
                                                 Wp1, Wp2, Wp3, Wp4, bp1, bp2, bp3, bp4);
  fm_pass_k<<<1024, 256, 0, stream>>>(fm, fmb, vis_sum, visb, use_fmb);

  // P1 = nonvis @ W1[:2048,:] + b1 ; snv = nonvis @ Ws[:2048,:] + bs
  gemm64_pair_k<E_BIAS | E_WF32, E_BIAS | E_WF32><<<dim3(32, 16, 2), 256, 0, stream>>>(
      nonvis_b, W1nv_t, P1, nullptr, nullptr, b1, nullptr, nullptr, 2048, 2048, 32,
      nonvis_b, Wsnv_t, snv, nullptr, nullptr, bs_pad, nullptr, nullptr, 128, 2048, 2);

  // ---- 5 iterations ----
  for (int it = 0; it < 5; ++it) {
    // x1 = bn(relu(vis@W1v + P1)) ; mi = hb@Uk + br   (independent -> one launch)
    gemm64_pair_k<E_CADD | E_RELU | E_AFF | E_WBF, E_BIAS | E_WF32>
        <<<dim3(48, 16, 2), 256, 0, stream>>>(
        visb, W1v_t, nullptr, x1, P1, nullptr, scale1, shift1, 2048, 1024, 32,
        hb, Ukt, mi, nullptr, nullptr, br, nullptr, nullptr, 3072, 1024, 48);
    gemm64_k<E_BIAS | E_RELU | E_AFF | E_WBF><<<dim3(16, 16), 256, 0, stream>>>(
        x1, W2t, nullptr, x2, nullptr, b2, scale2, shift2, 1024, 2048);
    gemm64_k<E_BIAS | E_WF32><<<dim3(48, 16), 256, 0, stream>>>(
        x2, Wkt, mx, nullptr, nullptr, bi, nullptr, nullptr, 3072, 1024);
    gru_k<<<4096, 256, 0, stream>>>(mx, mi, hf, hb);
    gemm64_k<E_BIAS | E_RELU | E_WBF><<<dim3(16, 16), 256, 0, stream>>>(
        hb, Wp1, nullptr, a1, nullptr, bp1, nullptr, nullptr, 1024, 1024);
    gemm64_k<E_BIAS | E_RELU | E_WBF><<<dim3(16, 16), 256, 0, stream>>>(
        a1, Wp2, nullptr, a2, nullptr, bp2, nullptr, nullptr, 1024, 1024);
    gemm64_k<E_BIAS | E_RELU | E_WBF><<<dim3(16, 16), 256, 0, stream>>>(
        a2, Wp3, nullptr, a3, nullptr, bp3, nullptr, nullptr, 1024, 1024);
    gemm64_k<E_BIAS | E_WF32><<<dim3(4, 16), 256, 0, stream>>>(
        a3, Wp4, a4, nullptr, nullptr, bp4, nullptr, nullptr, 256, 1024);
    attn_k<<<1024, 128, 0, stream>>>(a4, attn);
    if (use_fmb)
      wsum_bf16_k<<<1024, 256, 0, stream>>>(fmb, attn, vis_sum, visb, vsb);
    else
      wsum_f32_k<<<1024, 256, 0, stream>>>(fm, attn, vis_sum, visb, vsb);
  }

  // ---- final: out = snv + (vis_sum @ Wsv)/6 + prior ----
  gemm64_k<E_WF32><<<dim3(2, 16), 256, 0, stream>>>(
      vsb, Wsv_t, V, nullptr, nullptr, nullptr, nullptr, nullptr, 128, 1024);
  final_k<<<204, 256, 0, stream>>>(V, snv, prior, (float*)d_out);
}

// Round 3
// 1115.823 us; speedup vs baseline: 1.5610x; 1.0309x over previous
//
#include <hip/hip_runtime.h>

typedef unsigned short u16;
typedef __attribute__((ext_vector_type(8))) __bf16 bf16x8;
typedef __attribute__((ext_vector_type(4))) float f32x4;

typedef __attribute__((address_space(1))) const void gvoid_t;
typedef __attribute__((address_space(3))) void lvoid_t;

enum { E_CADD = 1, E_BIAS = 2, E_RELU = 4, E_AFF = 8, E_WBF = 16, E_WF32 = 32 };

static __device__ __forceinline__ u16 f2bf(float f) {
  unsigned u = __float_as_uint(f);
  u += 0x7fffu + ((u >> 16) & 1u);
  return (u16)(u >> 16);
}
static __device__ __forceinline__ float bf2f(u16 h) {
  return __uint_as_float(((unsigned)h) << 16);
}

// ---------------- 64xBN-tile bf16 MFMA GEMM body, 8 waves (512 thr) ----------
// C = epi(A @ Bt^T). A: M x K row-major bf16, Bt: N x K row-major bf16.
// Double-buffered LDS + 2-phase prefetch (stage next K-tile before computing
// current; single barrier per K-step whose implicit vmcnt(0) drains the
// prefetch). XOR-swizzled tiles: linear gload_lds dest + pre-swizzled SOURCE
// column-group, same XOR on ds_read (rule 21 / T2).
template <int FLAGS, int BN>
static __device__ __forceinline__ void gemmX_body(
    u16* As, u16* Bs,
    const u16* __restrict__ A, const u16* __restrict__ Bt,
    float* __restrict__ Cf, u16* __restrict__ Cb,
    const float* __restrict__ Cadd, const float* __restrict__ bias,
    const float* __restrict__ scale, const float* __restrict__ shift,
    int N, int K, int bx, int by) {
  const int tid = threadIdx.x;           // 0..511
  const int wave = tid >> 6, lane = tid & 63;
  const int bm = by << 6, bn = bx * BN;
  const int lr = lane & 15, lg = lane >> 4;
  const int rx = lr & 7;
  // wave tiling: BN=64 -> 4Mx2N waves of 16x32 (acc 1x2);
  //              BN=128 -> 2Mx4N waves of 32x32 (acc 2x2)
  const int wm = (BN == 64) ? ((wave >> 1) << 4) : ((wave >> 2) << 5);
  const int wn = (BN == 64) ? ((wave & 1) << 5) : ((wave & 3) << 5);
  constexpr int MI = (BN == 64) ? 1 : 2;
  constexpr int NB = BN / 64;            // B-tile load iters

  f32x4 acc[MI][2] = {};

  auto stage = [&](int buf, int kt) {
    {  // A: 64x64 tile, 512 chunks of 8 elems -> 1 per thread
      const int row = tid >> 3;
      const int cg = (tid & 7) ^ (row & 7);
      __builtin_amdgcn_global_load_lds(
          (gvoid_t*)(A + (size_t)(bm + row) * K + kt + (cg << 3)),
          (lvoid_t*)(As + buf * 4096 + wave * 512), 16, 0, 0);
    }
#pragma unroll
    for (int i = 0; i < NB; ++i) {  // B: BNx64 tile
      const int li = i * 512 + tid;
      const int row = li >> 3;
      const int cg = (li & 7) ^ (row & 7);
      __builtin_amdgcn_global_load_lds(
          (gvoid_t*)(Bt + (size_t)(bn + row) * K + kt + (cg << 3)),
          (lvoid_t*)(Bs + buf * (BN * 64) + i * 4096 + wave * 512), 16, 0, 0);
    }
  };

  stage(0, 0);
  int buf = 0;
  for (int kt = 0; kt < K; kt += 64) {
    __syncthreads();  // drains vmcnt(0): buf's loads done; prev reads done
    if (kt + 64 < K) stage(buf ^ 1, kt + 64);
    const u16* Ab = As + buf * 4096;
    const u16* Bb = Bs + buf * (BN * 64);
#pragma unroll
    for (int kk = 0; kk < 64; kk += 32) {
      bf16x8 av[MI], bv[2];
#pragma unroll
      for (int mi = 0; mi < MI; ++mi)
        av[mi] = *(const bf16x8*)(Ab + ((wm + mi * 16 + lr) << 6) +
                                  ((((kk >> 3) + lg) ^ rx) << 3));
#pragma unroll
      for (int ni = 0; ni < 2; ++ni)
        bv[ni] = *(const bf16x8*)(Bb + ((wn + ni * 16 + lr) << 6) +
                                  ((((kk >> 3) + lg) ^ rx) << 3));
#pragma unroll
      for (int mi = 0; mi < MI; ++mi)
#pragma unroll
        for (int ni = 0; ni < 2; ++ni)
          acc[mi][ni] = __builtin_amdgcn_mfma_f32_16x16x32_bf16(av[mi], bv[ni], acc[mi][ni], 0, 0, 0);
    }
    buf ^= 1;
  }

#pragma unroll
  for (int mi = 0; mi < MI; ++mi) {
#pragma unroll
    for (int ni = 0; ni < 2; ++ni) {
      const int col = bn + wn + ni * 16 + lr;
#pragma unroll
      for (int r = 0; r < 4; ++r) {
        const int row = bm + wm + mi * 16 + (lg << 2) + r;
        float v = acc[mi][ni][r];
        if (FLAGS & E_CADD) v += Cadd[(size_t)row * N + col];
        if (FLAGS & E_BIAS) v += bias[col];
        if (FLAGS & E_RELU) v = fmaxf(v, 0.f);
        if (FLAGS & E_AFF) v = v * scale[col] + shift[col];
        if (FLAGS & E_WF32) Cf[(size_t)row * N + col] = v;
        if (FLAGS & E_WBF) Cb[(size_t)row * N + col] = f2bf(v);
      }
    }
  }
}

template <int FLAGS, int BN>
__global__ __launch_bounds__(512) void gemmX_k(
    const u16* __restrict__ A, const u16* __restrict__ Bt,
    float* __restrict__ Cf, u16* __restrict__ Cb,
    const float* __restrict__ Cadd, const float* __restrict__ bias,
    const float* __restrict__ scale, const float* __restrict__ shift,
    int N, int K) {
  __shared__ u16 As[2 * 4096];
  __shared__ u16 Bs[2 * BN * 64];
  gemmX_body<FLAGS, BN>(As, Bs, A, Bt, Cf, Cb, Cadd, bias, scale, shift, N, K,
                        blockIdx.x, blockIdx.y);
}

// Two independent GEMMs in one launch (blockIdx.z selects).
template <int F0, int BN0, int F1, int BN1>
__global__ __launch_bounds__(512) void gemmX_pair_k(
    const u16* A0, const u16* B0, float* Cf0, u16* Cb0, const float* Cadd0,
    const float* bias0, const float* scale0, const float* shift0, int N0, int K0, int xt0,
    const u16* A1, const u16* B1, float* Cf1, u16* Cb1, const float* Cadd1,
    const float* bias1, const float* scale1, const float* shift1, int N1, int K1, int xt1) {
  constexpr int BMAX = (BN0 > BN1) ? BN0 : BN1;
  __shared__ u16 As[2 * 4096];
  __shared__ u16 Bs[2 * BMAX * 64];
  if (blockIdx.z == 0) {
    if ((int)blockIdx.x < xt0)
      gemmX_body<F0, BN0>(As, Bs, A0, B0, Cf0, Cb0, Cadd0, bias0, scale0, shift0,
                          N0, K0, blockIdx.x, blockIdx.y);
  } else {
    if ((int)blockIdx.x < xt1)
      gemmX_body<F1, BN1>(As, Bs, A1, B1, Cf1, Cb1, Cadd1, bias1, scale1, shift1,
                          N1, K1, blockIdx.x, blockIdx.y);
  }
}

// ---------------- all weight transposes (fp32 (K,N) slice -> bf16 (N,K)) ----
__global__ __launch_bounds__(256) void prep_w_k(
    const float* __restrict__ W1, const float* __restrict__ W2,
    const float* __restrict__ Wk, const float* __restrict__ Uk,
    const float* __restrict__ Ws,
    u16* __restrict__ W1nv_t, u16* __restrict__ W1v_t, u16* __restrict__ W2t,
    u16* __restrict__ Wkt, u16* __restrict__ Ukt,
    u16* __restrict__ Wsnv_t, u16* __restrict__ Wsv_t) {
  int b = blockIdx.x;
  const float* in; u16* out; int ld, k0, K, Nv, kT;
  if (b < 1024)      {           in = W1; out = W1nv_t; ld = 2048; k0 = 0;    K = 2048; Nv = 2048; kT = 32; }
  else if (b < 1536) { b -= 1024; in = W1; out = W1v_t;  ld = 2048; k0 = 2048; K = 1024; Nv = 2048; kT = 16; }
  else if (b < 2048) { b -= 1536; in = W2; out = W2t;   ld = 1024; k0 = 0;    K = 2048; Nv = 1024; kT = 32; }
  else if (b < 2816) { b -= 2048; in = Wk; out = Wkt;   ld = 3072; k0 = 0;    K = 1024; Nv = 3072; kT = 16; }
  else if (b < 3584) { b -= 2816; in = Uk; out = Ukt;   ld = 3072; k0 = 0;    K = 1024; Nv = 3072; kT = 16; }
  else if (b < 3648) { b -= 3584; in = Ws; out = Wsnv_t; ld = 51;  k0 = 0;    K = 2048; Nv = 51;   kT = 32; }
  else               { b -= 3648; in = Ws; out = Wsv_t;  ld = 51;  k0 = 2048; K = 1024; Nv = 51;   kT = 16; }
  const int kt = (b % kT) << 6, nt = (b / kT) << 6;
  __shared__ float t[64][65];
  const int tx = threadIdx.x & 63, ty = threadIdx.x >> 6;
#pragma unroll
  for (int i = 0; i < 16; ++i) {
    const int kl = ty + i * 4;
    const int n = nt + tx;
    t[kl][tx] = (n < Nv) ? in[(size_t)(k0 + kt + kl) * ld + n] : 0.f;
  }
  __syncthreads();
#pragma unroll
  for (int i = 0; i < 16; ++i)
    out[(size_t)(nt + ty + i * 4) * K + kt + tx] = f2bf(t[tx][ty + i * 4]);
}

// ---------------- pack all 4 convT(stride2,k3,SAME) weight layers ------------
// out pixel p even: w[0]*x[p/2-1] + w[2]*x[p/2];  p odd: w[1]*x[(p-1)/2]
__global__ void build_all_k(
    const float* __restrict__ w1, const float* __restrict__ b1c,
    const float* __restrict__ w2, const float* __restrict__ b2c,
    const float* __restrict__ w3, const float* __restrict__ b3c,
    const float* __restrict__ w4, const float* __restrict__ b4c,
    u16* __restrict__ Wp1, u16* __restrict__ Wp2,
    u16* __restrict__ Wp3, u16* __restrict__ Wp4,
    float* __restrict__ bp1, float* __restrict__ bp2,
    float* __restrict__ bp3, float* __restrict__ bp4) {
  int y = blockIdx.y;
  const float* w; const float* bin; u16* wp; float* bp; int Si, CI, CO, n;
  if (y < 1024)      { n = y;        w = w1; bin = b1c; wp = Wp1; bp = bp1; Si = 1; CI = 1024; CO = 256; }
  else if (y < 2048) { n = y - 1024; w = w2; bin = b2c; wp = Wp2; bp = bp2; Si = 2; CI = 256;  CO = 64; }
  else if (y < 3072) { n = y - 2048; w = w3; bin = b3c; wp = Wp3; bp = bp3; Si = 4; CI = 64;   CO = 16; }
  else               { n = y - 3072; w = w4; bin = b4c; wp = Wp4; bp = bp4; Si = 8; CI = 16;   CO = 1; }
  const int So = Si * 2;
  const int K = Si * Si * CI;  // = 1024 for all layers
  const int k = blockIdx.x * 256 + threadIdx.x;
  const int co = n % CO;
  const int pox = (n / CO) % So;
  const int poy = n / (CO * So);
  const int ci = k % CI;
  const int pix = (k / CI) % Si;
  const int piy = k / (CI * Si);
  int wy = -1, wx = -1;
  if (poy & 1) { if (piy == (poy >> 1)) wy = 1; }
  else { if (piy == (poy >> 1)) wy = 2; else if (piy == (poy >> 1) - 1) wy = 0; }
  if (pox & 1) { if (pix == (pox >> 1)) wx = 1; }
  else { if (pix == (pox >> 1)) wx = 2; else if (pix == (pox >> 1) - 1) wx = 0; }
  float v = 0.f;
  if (wy >= 0 && wx >= 0) v = w[((size_t)(wy * 3 + wx) * CI + ci) * CO + co];
  wp[(size_t)n * K + k] = f2bf(v);
  if (k == 0) bp[n] = bin[co];
}

// ---------------- featuremap pass: mean (vis0), bf16 copy ----------------
__global__ __launch_bounds__(256) void fm_pass_k(
    const float* __restrict__ fm, u16* __restrict__ fmb,
    float* __restrict__ vis_sum, u16* __restrict__ visb, int wfmb) {
  const int b = blockIdx.x;
  const int d0 = threadIdx.x << 2;
  const float* p = fm + (size_t)b * 102400 + d0;
  float s0 = 0, s1 = 0, s2 = 0, s3 = 0;
  for (int pp = 0; pp < 100; ++pp) {
    const float4 v = *(const float4*)(p + pp * 1024);
    if (wfmb) {
      ushort4 u;
      u.x = f2bf(v.x); u.y = f2bf(v.y); u.z = f2bf(v.z); u.w = f2bf(v.w);
      *(ushort4*)(fmb + (size_t)b * 102400 + pp * 1024 + d0) = u;
    }
    s0 += v.x; s1 += v.y; s2 += v.z; s3 += v.w;
  }
  const float inv = 1.0f / 100.0f;
  s0 *= inv; s1 *= inv; s2 *= inv; s3 *= inv;
  const int o = (b << 10) + d0;
  float4 m; m.x = s0; m.y = s1; m.z = s2; m.w = s3;
  *(float4*)(vis_sum + o) = m;
  ushort4 u; u.x = f2bf(s0); u.y = f2bf(s1); u.z = f2bf(s2); u.w = f2bf(s3);
  *(ushort4*)(visb + o) = u;
}

// ---------------- nonvis cast + BN constants + h init ----------------
__global__ __launch_bounds__(256) void misc_k(
    const float* __restrict__ nonvis, u16* __restrict__ nonvis_b,
    const float* g1, const float* be1, const float* m1, const float* v1,
    const float* g2, const float* be2, const float* m2, const float* v2,
    const float* bs, float* scale1, float* shift1, float* scale2, float* shift2,
    float* bs_pad, float* __restrict__ hf, u16* __restrict__ hb) {
  const int i = blockIdx.x * 256 + threadIdx.x;
  if (i < 2097152) nonvis_b[i] = f2bf(nonvis[i]);
  if (i < 1048576) { hf[i] = 0.f; hb[i] = 0; }
  if (i < 2048) { float sc = g1[i] * rsqrtf(v1[i] + 1e-3f); scale1[i] = sc; shift1[i] = be1[i] - m1[i] * sc; }
  if (i < 1024) { float sc = g2[i] * rsqrtf(v2[i] + 1e-3f); scale2[i] = sc; shift2[i] = be2[i] - m2[i] * sc; }
  if (i < 128) bs_pad[i] = (i < 51) ? bs[i] : 0.f;
}

// ---------------- GRU elementwise ----------------
__global__ __launch_bounds__(256) void gru_k(const float* __restrict__ mx, const float* __restrict__ mi,
                                             float* __restrict__ hf, u16* __restrict__ hb) {
  const int idx = blockIdx.x * 256 + threadIdx.x;  // B*D
  const int b = idx >> 10, d = idx & 1023;
  const float* mxb = mx + (size_t)b * 3072;
  const float* mib = mi + (size_t)b * 3072;
  const float xz = mxb[d], xr = mxb[d + 1024], xh = mxb[d + 2048];
  const float iz = mib[d], ir = mib[d + 1024], ih = mib[d + 2048];
  const float zg = 1.f / (1.f + expf(-(xz + iz)));
  const float rg = 1.f / (1.f + expf(-(xr + ir)));
  const float hh = tanhf(xh + rg * ih);
  const float hn = zg * hf[idx] + (1.f - zg) * hh;
  hf[idx] = hn;
  hb[idx] = f2bf(hn);
}

// ---------------- bilinear(16->10, antialias) + softmax(100) ----------------
static __device__ __forceinline__ void taps(int o, int& si, float* w) {
  const float s = 1.6f * (float)o + 0.3f;
  int s0 = (int)ceilf(s - 1.6f);
  if (s0 < 0) s0 = 0;
  si = s0;
  float sum = 0.f;
#pragma unroll
  for (int j = 0; j < 4; ++j) {
    const int i = s0 + j;
    float ww = 0.f;
    if (i <= 15) {
      const float d = fabsf(s - (float)i) * (1.0f / 1.6f);
      ww = fmaxf(0.f, 1.f - d);
    }
    w[j] = ww;
    sum += ww;
  }
  const float inv = 1.f / sum;
#pragma unroll
  for (int j = 0; j < 4; ++j) w[j] *= inv;
}

__global__ __launch_bounds__(128) void attn_k(const float* __restrict__ a4, float* __restrict__ attn) {
  const int b = blockIdx.x, t = threadIdx.x;
  __shared__ float sm[128];
  float val = -1e30f;
  if (t < 100) {
    const int oy = t / 10, ox = t - oy * 10;
    int siy, six;
    float wy[4], wx[4];
    taps(oy, siy, wy);
    taps(ox, six, wx);
    const float* p = a4 + (b << 8);
    float s = 0.f;
#pragma unroll
    for (int jy = 0; jy < 4; ++jy) {
      const int iy = min(siy + jy, 15);
      float rs = 0.f;
#pragma unroll
      for (int jx = 0; jx < 4; ++jx) {
        const int ix = min(six + jx, 15);
        rs += wx[jx] * p[(iy << 4) + ix];
      }
      s += wy[jy] * rs;
    }
    val = s;
  }
  sm[t] = val;
  __syncthreads();
  for (int off = 64; off > 0; off >>= 1) {
    if (t < off) sm[t] = fmaxf(sm[t], sm[t + off]);
    __syncthreads();
  }
  const float mx = sm[0];
  __syncthreads();
  const float e = (t < 100) ? expf(val - mx) : 0.f;
  sm[t] = e;
  __syncthreads();
  for (int off = 64; off > 0; off >>= 1) {
    if (t < off) sm[t] += sm[t + off];
    __syncthreads();
  }
  if (t < 100) attn[b * 100 + t] = e / sm[0];
}

// ------- vis = sum_p attn[p]*fm[p,:]; vis_sum += vis; vsb = bf16(vis_sum) ----
__global__ __launch_bounds__(256) void wsum_bf16_k(const u16* __restrict__ fmb,
                                                   const float* __restrict__ attn,
                                                   float* __restrict__ vis_sum,
                                                   u16* __restrict__ visb,
                                                   u16* __restrict__ vsb) {
  const int b = blockIdx.x;
  __shared__ float at[100];
  if (threadIdx.x < 100) at[threadIdx.x] = attn[b * 100 + threadIdx.x];
  __syncthreads();
  const int d0 = threadIdx.x << 2;
  const u16* p = fmb + (size_t)b * 102400 + d0;
  float s0 = 0, s1 = 0, s2 = 0, s3 = 0;
  for (int pp = 0; pp < 100; ++pp) {
    const ushort4 v = *(const ushort4*)(p + pp * 1024);
    const float a = at[pp];
    s0 += a * bf2f(v.x); s1 += a * bf2f(v.y); s2 += a * bf2f(v.z); s3 += a * bf2f(v.w);
  }
  const int o = (b << 10) + d0;
  float4 vs = *(float4*)(vis_sum + o);
  vs.x += s0; vs.y += s1; vs.z += s2; vs.w += s3;
  *(float4*)(vis_sum + o) = vs;
  ushort4 u; u.x = f2bf(s0); u.y = f2bf(s1); u.z = f2bf(s2); u.w = f2bf(s3);
  *(ushort4*)(visb + o) = u;
  ushort4 w; w.x = f2bf(vs.x); w.y = f2bf(vs.y); w.z = f2bf(vs.z); w.w = f2bf(vs.w);
  *(ushort4*)(vsb + o) = w;
}

__global__ __launch_bounds__(256) void wsum_f32_k(const float* __restrict__ fm,
                                                  const float* __restrict__ attn,
                                                  float* __restrict__ vis_sum,
                                                  u16* __restrict__ visb,
                                                  u16* __restrict__ vsb) {
  const int b = blockIdx.x;
  __shared__ float at[100];
  if (threadIdx.x < 100) at[threadIdx.x] = attn[b * 100 + threadIdx.x];
  __syncthreads();
  const int d0 = threadIdx.x << 2;
  const float* p = fm + (size_t)b * 102400 + d0;
  float s0 = 0, s1 = 0, s2 = 0, s3 = 0;
  for (int pp = 0; pp < 100; ++pp) {
    const float4 v = *(const float4*)(p + pp * 1024);
    const float a = at[pp];
    s0 += a * v.x; s1 += a * v.y; s2 += a * v.z; s3 += a * v.w;
  }
  const int o = (b << 10) + d0;
  float4 vs = *(float4*)(vis_sum + o);
  vs.x += s0; vs.y += s1; vs.z += s2; vs.w += s3;
  *(float4*)(vis_sum + o) = vs;
  ushort4 u; u.x = f2bf(s0); u.y = f2bf(s1); u.z = f2bf(s2); u.w = f2bf(s3);
  *(ushort4*)(visb + o) = u;
  ushort4 w; w.x = f2bf(vs.x); w.y = f2bf(vs.y); w.z = f2bf(vs.z); w.w = f2bf(vs.w);
  *(ushort4*)(vsb + o) = w;
}

// ---------------- out = V/6 + score_nv + prior ----------------
__global__ void final_k(const float* __restrict__ V, const float* __restrict__ snv,
                        const float* __restrict__ prior, float* __restrict__ out) {
  const int idx = blockIdx.x * 256 + threadIdx.x;
  if (idx >= 1024 * 51) return;
  const int b = idx / 51, n = idx - b * 51;
  out[idx] = V[(b << 7) + n] * (1.f / 6.f) + snv[(b << 7) + n] + prior[idx];
}

extern "C" void kernel_launch(void* const* d_in, const int* in_sizes, int n_in,
                              void* d_out, int out_size, void* d_ws, size_t ws_size,
                              hipStream_t stream) {
  (void)in_sizes; (void)n_in; (void)out_size;
  const float* nonvis = (const float*)d_in[0];
  const float* fm     = (const float*)d_in[1];
  const float* prior  = (const float*)d_in[2];
  const float* W1     = (const float*)d_in[3];
  const float* b1     = (const float*)d_in[4];
  const float* g1     = (const float*)d_in[5];
  const float* be1    = (const float*)d_in[6];
  const float* m1     = (const float*)d_in[7];
  const float* v1     = (const float*)d_in[8];
  const float* W2     = (const float*)d_in[9];
  const float* b2     = (const float*)d_in[10];
  const float* g2     = (const float*)d_in[11];
  const float* be2    = (const float*)d_in[12];
  const float* m2     = (const float*)d_in[13];
  const float* v2     = (const float*)d_in[14];
  const float* Wk     = (const float*)d_in[15];
  const float* Uk     = (const float*)d_in[16];
  const float* bi     = (const float*)d_in[17];
  const float* br     = (const float*)d_in[18];
  const float* ct1w   = (const float*)d_in[19];
  const float* ct1b   = (const float*)d_in[20];
  const float* ct2w   = (const float*)d_in[21];
  const float* ct2b   = (const float*)d_in[22];
  const float* ct3w   = (const float*)d_in[23];
  const float* ct3b   = (const float*)d_in[24];
  const float* ct4w   = (const float*)d_in[25];
  const float* ct4b   = (const float*)d_in[26];
  const float* Ws     = (const float*)d_in[27];
  const float* bs     = (const float*)d_in[28];

  char* base = (char*)d_ws;
  size_t off = 0;
  auto alloc = [&](size_t bytes) -> void* {
    void* r = base + off;
    off = (off + bytes + 255) & ~(size_t)255;
    return r;
  };

  u16* nonvis_b = (u16*)alloc(4194304);
  u16* W1nv_t   = (u16*)alloc(8388608);
  u16* W1v_t    = (u16*)alloc(4194304);
  u16* W2t      = (u16*)alloc(4194304);
  u16* Wkt      = (u16*)alloc(6291456);
  u16* Ukt      = (u16*)alloc(6291456);
  u16* Wsnv_t   = (u16*)alloc(524288);
  u16* Wsv_t    = (u16*)alloc(262144);
  u16* Wp1      = (u16*)alloc(2097152);
  u16* Wp2      = (u16*)alloc(2097152);
  u16* Wp3      = (u16*)alloc(2097152);
  u16* Wp4      = (u16*)alloc(524288);
  float* bp1    = (float*)alloc(4096);
  float* bp2    = (float*)alloc(4096);
  float* bp3    = (float*)alloc(4096);
  float* bp4    = (float*)alloc(1024);
  float* scale1 = (float*)alloc(8192);
  float* shift1 = (float*)alloc(8192);
  float* scale2 = (float*)alloc(4096);
  float* shift2 = (float*)alloc(4096);
  float* bs_pad = (float*)alloc(512);
  float* P1     = (float*)alloc(8388608);
  float* snv    = (float*)alloc(524288);
  u16* x1       = (u16*)alloc(4194304);
  u16* x2       = (u16*)alloc(2097152);
  float* mx     = (float*)alloc(12582912);
  float* mi     = (float*)alloc(12582912);
  float* hf     = (float*)alloc(4194304);
  u16* hb       = (u16*)alloc(2097152);
  u16* a1       = (u16*)alloc(2097152);
  u16* a2       = (u16*)alloc(2097152);
  u16* a3       = (u16*)alloc(2097152);
  float* a4     = (float*)alloc(1048576);
  float* attn   = (float*)alloc(409600);
  float* vis_sum= (float*)alloc(4194304);
  u16* visb     = (u16*)alloc(2097152);
  u16* vsb      = (u16*)alloc(2097152);
  float* V      = (float*)alloc(524288);
  u16* fmb = nullptr;
  int use_fmb = 0;
  if (off + (size_t)209715200 + 256 <= ws_size) {
    fmb = (u16*)alloc(209715200);
    use_fmb = 1;
  }

  // ---- setup ----
  misc_k<<<8192, 256, 0, stream>>>(nonvis, nonvis_b, g1, be1, m1, v1, g2, be2, m2, v2,
                                   bs, scale1, shift1, scale2, shift2, bs_pad, hf, hb);
  prep_w_k<<<3680, 256, 0, stream>>>(W1, W2, Wk, Uk, Ws,
                                     W1nv_t, W1v_t, W2t, Wkt, Ukt, Wsnv_t, Wsv_t);
  build_all_k<<<dim3(4, 3328), 256, 0, stream>>>(ct1w, ct1b, ct2w, ct2b, ct3w, ct3b, ct4w, ct4b,
                                                 Wp1, Wp2, Wp3, Wp4, bp1, bp2, bp3, bp4);
  fm_pass_k<<<1024, 256, 0, stream>>>(fm, fmb, vis_sum, visb, use_fmb);

  // P1 = nonvis @ W1[:2048,:] + b1 ; snv = nonvis @ Ws[:2048,:] + bs
  gemmX_pair_k<E_BIAS | E_WF32, 128, E_BIAS | E_WF32, 128><<<dim3(16, 16, 2), 512, 0, stream>>>(
      nonvis_b, W1nv_t, P1, nullptr, nullptr, b1, nullptr, nullptr, 2048, 2048, 16,
      nonvis_b, Wsnv_t, snv, nullptr, nullptr, bs_pad, nullptr, nullptr, 128, 2048, 1);

  // ---- 5 iterations ----
  for (int it = 0; it < 5; ++it) {
    // x1 = bn(relu(vis@W1v + P1)) ; mi = hb@Uk + br   (independent -> one launch)
    gemmX_pair_k<E_CADD | E_RELU | E_AFF | E_WBF, 128, E_BIAS | E_WF32, 128>
        <<<dim3(24, 16, 2), 512, 0, stream>>>(
        visb, W1v_t, nullptr, x1, P1, nullptr, scale1, shift1, 2048, 1024, 16,
        hb, Ukt, mi, nullptr, nullptr, br, nullptr, nullptr, 3072, 1024, 24);
    gemmX_k<E_BIAS | E_RELU | E_AFF | E_WBF, 64><<<dim3(16, 16), 512, 0, stream>>>(
        x1, W2t, nullptr, x2, nullptr, b2, scale2, shift2, 1024, 2048);
    gemmX_k<E_BIAS | E_WF32, 128><<<dim3(24, 16), 512, 0, stream>>>(
        x2, Wkt, mx, nullptr, nullptr, bi, nullptr, nullptr, 3072, 1024);
    gru_k<<<4096, 256, 0, stream>>>(mx, mi, hf, hb);
    gemmX_k<E_BIAS | E_RELU | E_WBF, 64><<<dim3(16, 16), 512, 0, stream>>>(
        hb, Wp1, nullptr, a1, nullptr, bp1, nullptr, nullptr, 1024, 1024);
    gemmX_k<E_BIAS | E_RELU | E_WBF, 64><<<dim3(16, 16), 512, 0, stream>>>(
        a1, Wp2, nullptr, a2, nullptr, bp2, nullptr, nullptr, 1024, 1024);
    gemmX_k<E_BIAS | E_RELU | E_WBF, 64><<<dim3(16, 16), 512, 0, stream>>>(
        a2, Wp3, nullptr, a3, nullptr, bp3, nullptr, nullptr, 1024, 1024);
    gemmX_k<E_BIAS | E_WF32, 64><<<dim3(4, 16), 512, 0, stream>>>(
        a3, Wp4, a4, nullptr, nullptr, bp4, nullptr, nullptr, 256, 1024);
    attn_k<<<1024, 128, 0, stream>>>(a4, attn);
    if (use_fmb)
      wsum_bf16_k<<<1024, 256, 0, stream>>>(fmb, attn, vis_sum, visb, vsb);
    else
      wsum_f32_k<<<1024, 256, 0, stream>>>(fm, attn, vis_sum, visb, vsb);
  }

  // ---- final: out = snv + (vis_sum @ Wsv)/6 + prior ----
  gemmX_k<E_WF32, 128><<<dim3(1, 16), 512, 0, stream>>>(
      vsb, Wsv_t, V, nullptr, nullptr, nullptr, nullptr, nullptr, 128, 1024);
  final_k<<<204, 256, 0, stream>>>(V, snv, prior, (float*)d_out);
}